// Round 2
// baseline (7193.076 us; speedup 1.0000x reference)
//
#include <hip/hip_runtime.h>
#include <hip/hip_fp16.h>
#include <stdint.h>

// LSTM policy rollout, weights-resident version.
// 256 blocks x 1024 threads, persistent. Each block owns 16 h-rows = 48 gate
// rows. Each of 16 waves owns 3 rows: 2 in VGPRs (f16 packed), 1 in LDS.
// Per-step global traffic = h exchange (24 KB) + flag barrier only.
// Grid sync = per-block epoch flags (release store / acquire poll).

#define HID    4096
#define CTX    1024
#define NSTEPS 256
#define NBLK   256
#define TPB    1024
#define WAVES  16
#define HROWS  16          // h rows per block
#define GROWS  48          // gate rows per block
#define NCH    8           // column chunks of 512

typedef _Float16 h2 __attribute__((ext_vector_type(2)));

__device__ __forceinline__ float fdot2f(uint32_t a, uint32_t b, float c) {
#if __has_builtin(__builtin_amdgcn_fdot2)
  return __builtin_amdgcn_fdot2(__builtin_bit_cast(h2, a),
                                __builtin_bit_cast(h2, b), c, false);
#else
  h2 x = __builtin_bit_cast(h2, a), y = __builtin_bit_cast(h2, b);
  return c + (float)x[0]*(float)y[0] + (float)x[1]*(float)y[1];
#endif
}
__device__ __forceinline__ uint32_t pkf16(float x, float y) {
  h2 v; v[0] = (_Float16)x; v[1] = (_Float16)y;
  return __builtin_bit_cast(uint32_t, v);
}

__global__ __launch_bounds__(TPB)
void lstm(const float* __restrict__ ctx, const float* __restrict__ u,
          const float* __restrict__ l1w, const float* __restrict__ l1b,
          const float* __restrict__ Wf,  const float* __restrict__ Wfb,
          const float* __restrict__ Wi,  const float* __restrict__ Wib,
          const float* __restrict__ Wc,  const float* __restrict__ Wcb,
          const float* __restrict__ Wow, const float* __restrict__ Wob,
          float* __restrict__ zb0f, float* __restrict__ zb1f,
          uint32_t* __restrict__ zb0h, uint32_t* __restrict__ zb1h,
          uint32_t* __restrict__ flags, float* __restrict__ out)
{
  __shared__ uint4 zsh4[HID/8];           // z as packed f16x2, 8 KB
  __shared__ float zshf[HID];             // z f32 (o-gate), 16 KB
  __shared__ uint4 wlds[WAVES][HID/8];    // 1 LDS-resident row per wave, 128 KB
  __shared__ float red[WAVES];
  __shared__ float pre[GROWS];
  __shared__ float cst[HROWS];
  __shared__ float bias[GROWS];
  __shared__ float wx[GROWS];             // column-4096 (x) weight per row
  __shared__ float hloc[HROWS];
  __shared__ float x0sh;

  const int tid  = threadIdx.x;
  const int b    = blockIdx.x;
  const int wv   = tid >> 6;
  const int lane = tid & 63;

  // ---- zero init ----
  {
    uint32_t* z32 = (uint32_t*)zsh4;
    for (int i = tid; i < HID/2; i += TPB) z32[i] = 0u;
    for (int i = tid; i < HID;   i += TPB) zshf[i] = 0.f;
    if (tid < HROWS) cst[tid] = 0.f;
  }
  if (tid < GROWS) {
    int g = tid / HROWS, j = tid % HROWS;
    const float* bw = (g==0 ? Wfb : (g==1 ? Wib : Wcb));
    const float* gw = (g==0 ? Wf  : (g==1 ? Wi  : Wc ));
    bias[tid] = bw[b*HROWS + j];
    wx[tid]   = gw[(size_t)(b*HROWS + j)*4097 + 4096];
  }

  // ---- o-gate weights resident in registers (step-invariant) ----
  float wow[4];
  #pragma unroll
  for (int k = 0; k < 4; ++k) wow[k] = Wow[tid + k*TPB];
  const float woxw = Wow[HID];
  const float wob0 = Wob[0];

  // ---- load + convert this wave's 3 gate rows: 2 -> VGPRs, 1 -> LDS ----
  uint4 wr0[NCH], wr1[NCH];
  {
    const int fl0 = wv*3;
    const int g0 = (fl0+0)/HROWS, j0 = (fl0+0)%HROWS;
    const int g1 = (fl0+1)/HROWS, j1 = (fl0+1)%HROWS;
    const int g2 = (fl0+2)/HROWS, j2 = (fl0+2)%HROWS;
    const float* r0 = (g0==0?Wf:(g0==1?Wi:Wc)) + (size_t)(b*HROWS+j0)*4097;
    const float* r1 = (g1==0?Wf:(g1==1?Wi:Wc)) + (size_t)(b*HROWS+j1)*4097;
    const float* r2 = (g2==0?Wf:(g2==1?Wi:Wc)) + (size_t)(b*HROWS+j2)*4097;
    #pragma unroll
    for (int c = 0; c < NCH; ++c) {
      const int col = c*512 + lane*8;
      float t[8];
      #pragma unroll
      for (int e = 0; e < 8; ++e) t[e] = r0[col+e];
      wr0[c] = make_uint4(pkf16(t[0],t[1]), pkf16(t[2],t[3]),
                          pkf16(t[4],t[5]), pkf16(t[6],t[7]));
      #pragma unroll
      for (int e = 0; e < 8; ++e) t[e] = r1[col+e];
      wr1[c] = make_uint4(pkf16(t[0],t[1]), pkf16(t[2],t[3]),
                          pkf16(t[4],t[5]), pkf16(t[6],t[7]));
      #pragma unroll
      for (int e = 0; e < 8; ++e) t[e] = r2[col+e];
      wlds[wv][c*64 + lane] = make_uint4(pkf16(t[0],t[1]), pkf16(t[2],t[3]),
                                         pkf16(t[4],t[5]), pkf16(t[6],t[7]));
    }
  }

  // ---- x0 = l1_w . context + l1_b (identical in every block) ----
  {
    float p = l1w[tid] * ctx[tid];      // CTX == TPB
    #pragma unroll
    for (int off = 32; off; off >>= 1) p += __shfl_down(p, off, 64);
    __syncthreads();                     // also covers zero-init + wlds
    if (lane == 0) red[wv] = p;
    __syncthreads();
    if (tid == 0) {
      float ssum = 0.f;
      for (int w = 0; w < WAVES; ++w) ssum += red[w];
      x0sh = ssum + l1b[0];
    }
    __syncthreads();
  }
  float xcur = x0sh;
  float logp = 0.f;

  for (int t = 0; t < NSTEPS; ++t) {
    // ---- o gate (f32, bit-identical across blocks) ----
    float p = 0.f;
    #pragma unroll
    for (int k = 0; k < 4; ++k) p = fmaf(wow[k], zshf[tid + k*TPB], p);
    #pragma unroll
    for (int off = 32; off; off >>= 1) p += __shfl_down(p, off, 64);
    if (lane == 0) red[wv] = p;
    __syncthreads();
    float osum = 0.f;
    #pragma unroll
    for (int w = 0; w < WAVES; ++w) osum += red[w];
    const float opre = osum + woxw*xcur + wob0;
    const float o = 1.f / (1.f + expf(-opre));
    const float s = (u[t] < o) ? 1.f : 0.f;

    // ---- f/i/c gate dots from resident weights ----
    float a0 = 0.f, a1 = 0.f, a2 = 0.f;
    #pragma unroll
    for (int c = 0; c < NCH; ++c) {
      const uint4 zz = zsh4[c*64 + lane];
      const uint4 wl = wlds[wv][c*64 + lane];
      const uint4 w0 = wr0[c];
      const uint4 w1 = wr1[c];
      a0 = fdot2f(w0.x, zz.x, a0); a0 = fdot2f(w0.y, zz.y, a0);
      a0 = fdot2f(w0.z, zz.z, a0); a0 = fdot2f(w0.w, zz.w, a0);
      a1 = fdot2f(w1.x, zz.x, a1); a1 = fdot2f(w1.y, zz.y, a1);
      a1 = fdot2f(w1.z, zz.z, a1); a1 = fdot2f(w1.w, zz.w, a1);
      a2 = fdot2f(wl.x, zz.x, a2); a2 = fdot2f(wl.y, zz.y, a2);
      a2 = fdot2f(wl.z, zz.z, a2); a2 = fdot2f(wl.w, zz.w, a2);
    }
    #pragma unroll
    for (int off = 32; off; off >>= 1) {
      a0 += __shfl_down(a0, off, 64);
      a1 += __shfl_down(a1, off, 64);
      a2 += __shfl_down(a2, off, 64);
    }
    if (lane == 0) {
      const int fl = wv*3;
      pre[fl+0] = a0 + wx[fl+0]*xcur + bias[fl+0];
      pre[fl+1] = a1 + wx[fl+1]*xcur + bias[fl+1];
      pre[fl+2] = a2 + wx[fl+2]*xcur + bias[fl+2];
    }
    __syncthreads();

    // ---- h update ----
    float* hbF = (t & 1) ? zb1f : zb0f;
    uint32_t* hbH = (t & 1) ? zb1h : zb0h;
    if (tid < HROWS) {
      const float ff = 1.f / (1.f + expf(-pre[tid]));
      const float ii = 1.f / (1.f + expf(-pre[HROWS+tid]));
      const float cc = tanhf(pre[2*HROWS+tid]);
      const float cn = ff*cst[tid] + ii*cc;
      cst[tid] = cn;
      const float hv = o * tanhf(cn);
      hloc[tid] = hv;
      hbF[b*HROWS + tid] = hv;
    }
    __syncthreads();
    if (tid < HROWS/2)
      hbH[b*(HROWS/2) + tid] = pkf16(hloc[2*tid], hloc[2*tid+1]);
    if (b == 0 && tid == 0) {
      logp += (s != 0.f) ? logf(o) : logf(1.f - o);
      out[t] = s;
    }
    xcur = s;

    // ---- flag barrier: publish epoch, poll all 256 flags ----
    __syncthreads();   // drains vmcnt: h stores complete before publish
    if (tid == 0) {
      __threadfence();
      __hip_atomic_store(&flags[b], (uint32_t)(t+1), __ATOMIC_RELEASE,
                         __HIP_MEMORY_SCOPE_AGENT);
    }
    if (tid < NBLK) {
      while (__hip_atomic_load(&flags[tid], __ATOMIC_ACQUIRE,
                               __HIP_MEMORY_SCOPE_AGENT) < (uint32_t)(t+1))
        __builtin_amdgcn_s_sleep(2);
    }
    __syncthreads();

    // ---- gather z(t) for next step ----
    if (t + 1 < NSTEPS) {
      const float* rbf = hbF;
      const uint32_t* rb2 = hbH;
      uint32_t* z32 = (uint32_t*)zsh4;
      #pragma unroll
      for (int k = 0; k < 4; ++k) zshf[tid + k*TPB] = rbf[tid + k*TPB];
      #pragma unroll
      for (int k = 0; k < 2; ++k) z32[tid + k*TPB] = rb2[tid + k*TPB];
      __syncthreads();
    }
  }
  if (b == 0 && tid == 0) out[NSTEPS] = logp;
}

extern "C" void kernel_launch(void* const* d_in, const int* in_sizes, int n_in,
                              void* d_out, int out_size, void* d_ws, size_t ws_size,
                              hipStream_t stream) {
  const float* ctx = (const float*)d_in[0];
  const float* u   = (const float*)d_in[1];
  const float* l1w = (const float*)d_in[2];
  const float* l1b = (const float*)d_in[3];
  const float* Wf  = (const float*)d_in[4];
  const float* Wfb = (const float*)d_in[5];
  const float* Wi  = (const float*)d_in[6];
  const float* Wib = (const float*)d_in[7];
  const float* Wc  = (const float*)d_in[8];
  const float* Wcb = (const float*)d_in[9];
  const float* Wow = (const float*)d_in[10];
  const float* Wob = (const float*)d_in[11];
  float* out = (float*)d_out;

  char* ws = (char*)d_ws;
  uint32_t* flags = (uint32_t*)ws;                       // 1 KB used
  float*    zb0f  = (float*)(ws + 4096);
  float*    zb1f  = (float*)(ws + 4096 + HID*4);
  uint32_t* zb0h  = (uint32_t*)(ws + 4096 + 2*HID*4);
  uint32_t* zb1h  = (uint32_t*)(ws + 4096 + 2*HID*4 + HID*2);

  hipMemsetAsync(flags, 0, 4096, stream);
  lstm<<<NBLK, TPB, 0, stream>>>(ctx,u,l1w,l1b,Wf,Wfb,Wi,Wib,Wc,Wcb,Wow,Wob,
                                 zb0f,zb1f,zb0h,zb1h,flags,out);
}